// Round 6
// baseline (2894.624 us; speedup 1.0000x reference)
//
#include <hip/hip_runtime.h>

#define FD 128      // feature dim (both layers)
#define BSH 7       // log2(nodes per bucket) = 128 nodes/bucket
#define CH 2048     // edges per partition block
#define CHT 8       // edges per thread (CH / 256)
#define KMAX 512    // max buckets
#define SCAP 8192   // build_kernel LDS edge stage
#define NCH 8       // src chunk planes (chunk = src >> CSH); requires N <= 57344
#define CSH 13      // 8192 nodes/chunk -> 2 MB of h' per chunk (fits 4 MB per-XCD L2)
// packed pair: (local_dst << 17) | src   -- requires N <= 131072

typedef __attribute__((ext_vector_type(8))) short bf16x8;
typedef __attribute__((ext_vector_type(4))) float f32x4;

__device__ inline unsigned bfr(float f) {   // fp32 -> bf16 bits, round-nearest-even
    unsigned u = __float_as_uint(f);
    return (u + 0x7FFF + ((u >> 16) & 1)) >> 16;
}
__device__ inline float uplo(unsigned p) { return __uint_as_float(p << 16); }
__device__ inline float uphi(unsigned p) { return __uint_as_float(p & 0xFFFF0000u); }

// ---------------- CSR build ----------------
// R18: partition multi-split (1.0x write density) unchanged. build bins each
// bucket CHUNK-MAJOR (key = (chunk<<7)|row) and stores the full packed
// (row<<17)|src in col. Agg is bucket-parallel: block b owns bucket b's 128
// rows as LDS accumulators and streams the bucket's chunk-ordered edges with
// 16 gathers in flight; all 391 blocks are co-resident (2/CU at 64 KB LDS),
// sweeping src chunks together -> ~2 MB live gather window per XCD L2.

__global__ __launch_bounds__(256) void partition_kernel(
        const int* __restrict__ src, const int* __restrict__ dst,
        int* __restrict__ lstartG, int* __restrict__ total,
        int* __restrict__ pairs, int E, int K) {
    __shared__ int lcnt[KMAX];     // counts, then scatter cursor
    __shared__ int lstart[KMAX];   // local exclusive prefix
    __shared__ int sm[256];
    __shared__ int staged[CH];
    int t = threadIdx.x;
    int base = blockIdx.x * CH;
    int n = min(CH, E - base);

    lcnt[t] = 0; lcnt[t + 256] = 0;
    __syncthreads();

    int pk[CHT]; int bn[CHT];
    #pragma unroll
    for (int j = 0; j < CHT; ++j) {
        int i = t + j * 256;
        bn[j] = -1;
        if (i < n) {
            int d = dst[base + i];
            int s = src[base + i];
            bn[j] = d >> BSH;
            pk[j] = ((d & ((1 << BSH) - 1)) << 17) | s;
            atomicAdd(&lcnt[bn[j]], 1);
        }
    }
    __syncthreads();

    // exclusive scan of 512 bins, 2 consecutive bins per thread
    int c0 = lcnt[2 * t], c1 = lcnt[2 * t + 1];
    int s2 = c0 + c1;
    sm[t] = s2;
    __syncthreads();
    for (int off = 1; off < 256; off <<= 1) {
        int add = (t >= off) ? sm[t - off] : 0;
        __syncthreads();
        sm[t] += add;
        __syncthreads();
    }
    int ex = sm[t] - s2;
    lstart[2 * t] = ex;     lstart[2 * t + 1] = ex + c0;
    lcnt[2 * t]   = ex;     lcnt[2 * t + 1]   = ex + c0;   // cursor
    __syncthreads();

    // scatter chunk into staged[], sorted by bucket
    #pragma unroll
    for (int j = 0; j < CHT; ++j) {
        if (bn[j] >= 0) {
            int pos = atomicAdd(&lcnt[bn[j]], 1);
            staged[pos] = pk[j];
        }
    }
    __syncthreads();

    // sequential coalesced copy-out: this block owns pairs[base .. base+n)
    for (int i = t; i < n; i += 256)
        pairs[base + i] = staged[i];

    // per-block bucket boundaries + bucket totals
    size_t lrow = (size_t)blockIdx.x * (K + 1);
    for (int b = t; b < K; b += 256) {
        lstartG[lrow + b] = lstart[b];
        int c = lcnt[b] - lstart[b];
        if (c) atomicAdd(&total[b], c);
    }
    if (t == 0) lstartG[lrow + K] = n;
}

// exclusive scan of K bucket totals -> bbase
__global__ __launch_bounds__(512) void totscan_kernel(
        const int* __restrict__ total, int* __restrict__ bbase, int K, int E) {
    __shared__ int sm[512];
    int t = threadIdx.x;
    int v = (t < K) ? total[t] : 0;
    sm[t] = v;
    __syncthreads();
    for (int off = 1; off < 512; off <<= 1) {
        int add = (t >= off) ? sm[t - off] : 0;
        __syncthreads();
        sm[t] += add;
        __syncthreads();
    }
    if (t < K) bbase[t] = sm[t] - v;
    if (t == 0) bbase[K] = E;
}

// transpose A[R][C] -> B[C][R]  (lstartG [PB][K+1] -> lstartT [K+1][PB])
__global__ __launch_bounds__(256) void tr_kernel(
        const int* __restrict__ A, int* __restrict__ B, int R, int C) {
    __shared__ int tile[32][33];
    int c0 = blockIdx.x * 32, r0 = blockIdx.y * 32;
    int tx = threadIdx.x, ty = threadIdx.y;   // block (32, 8)
    for (int i = ty; i < 32; i += 8) {
        int r = r0 + i, c = c0 + tx;
        if (r < R && c < C) tile[i][tx] = A[(size_t)r * C + c];
    }
    __syncthreads();
    for (int i = ty; i < 32; i += 8) {
        int c = c0 + i, r = r0 + tx;
        if (c < C && r < R) B[(size_t)c * R + r] = tile[tx][i];
    }
}

// Per-bucket: gather fragments into LDS, bin CHUNK-MAJOR (key=(chunk<<7)|row),
// scan, write dis, scatter col keeping the full packed (row<<17)|src.
__global__ __launch_bounds__(256) void build_kernel(
        const int* __restrict__ pairs, const int* __restrict__ lstartT,
        const int* __restrict__ bbase, float* __restrict__ dis,
        int* __restrict__ col, int N, int PB, int K) {
    __shared__ int staged[SCAP];
    __shared__ int lcnt[128 * NCH];   // counts, then absolute scatter cursor
    __shared__ int pref[128 * NCH];   // bucket-local exclusive prefix
    __shared__ int sm[256];
    int b = blockIdx.x;
    int t = threadIdx.x;
    int nbase = b << BSH;
    int nn = min(1 << BSH, N - nbase);
    int beg = bbase[b];
    int cnt = bbase[b + 1] - beg;

    // fragment descriptors (coalesced reads from transposed lstart)
    int fp[4], fl0[4], flen[4];
    int nf = 0, mysum = 0;
    for (int p = t; p < PB; p += 256) {
        int l0 = lstartT[(size_t)b * PB + p];
        int l1 = lstartT[(size_t)(b + 1) * PB + p];
        fp[nf] = p; fl0[nf] = l0; flen[nf] = l1 - l0;
        mysum += l1 - l0;
        ++nf;
    }
    // exclusive scan of per-thread sums -> dest offsets in staged
    sm[t] = mysum;
    __syncthreads();
    for (int off = 1; off < 256; off <<= 1) {
        int add = (t >= off) ? sm[t - off] : 0;
        __syncthreads();
        sm[t] += add;
        __syncthreads();
    }
    int o = sm[t] - mysum;

    lcnt[t] = 0; lcnt[t + 256] = 0; lcnt[t + 512] = 0; lcnt[t + 768] = 0;

    if (cnt <= SCAP) {   // fast path (always, for Poisson buckets)
        for (int f = 0; f < nf; ++f) {
            int gbase = fp[f] * CH + fl0[f];
            for (int i = 0; i < flen[f]; ++i) staged[o + i] = pairs[gbase + i];
            o += flen[f];
        }
        __syncthreads();
        for (int i = t; i < cnt; i += 256) {
            int p = staged[i];
            atomicAdd(&lcnt[(((p & 0x1FFFF) >> CSH) << 7) | (p >> 17)], 1);
        }
    } else {             // overflow fallback: count directly from global
        __syncthreads();
        for (int f = 0; f < nf; ++f) {
            int gbase = fp[f] * CH + fl0[f];
            for (int i = 0; i < flen[f]; ++i) {
                int p = pairs[gbase + i];
                atomicAdd(&lcnt[(((p & 0x1FFFF) >> CSH) << 7) | (p >> 17)], 1);
            }
        }
    }
    __syncthreads();

    // exclusive scan of 1024 bins, 4 consecutive per thread
    int b0 = 4 * t;
    int c0 = lcnt[b0], c1 = lcnt[b0 + 1], c2 = lcnt[b0 + 2], c3 = lcnt[b0 + 3];
    int s4 = c0 + c1 + c2 + c3;
    sm[t] = s4;
    __syncthreads();
    for (int off = 1; off < 256; off <<= 1) {
        int add = (t >= off) ? sm[t - off] : 0;
        __syncthreads();
        sm[t] += add;
        __syncthreads();
    }
    int ex = sm[t] - s4;
    pref[b0] = ex; pref[b0 + 1] = ex + c0;
    pref[b0 + 2] = ex + c0 + c1; pref[b0 + 3] = ex + c0 + c1 + c2;
    __syncthreads();

    // dis: row degree = sum over 8 chunk planes (lcnt still holds raw counts)
    if (t < 128) {
        int deg = 0;
        #pragma unroll
        for (int pp = 0; pp < 8; ++pp) deg += lcnt[(pp << 7) | t];
        if (t < nn) dis[nbase + t] = rsqrtf((float)(deg + 1));  // + self-loop
    }
    __syncthreads();
    lcnt[b0]     = beg + pref[b0];
    lcnt[b0 + 1] = beg + pref[b0 + 1];
    lcnt[b0 + 2] = beg + pref[b0 + 2];
    lcnt[b0 + 3] = beg + pref[b0 + 3];
    __syncthreads();

    if (cnt <= SCAP) {
        for (int i = t; i < cnt; i += 256) {
            int p = staged[i];
            int key = (((p & 0x1FFFF) >> CSH) << 7) | (p >> 17);
            int pos = atomicAdd(&lcnt[key], 1);
            col[pos] = p;   // full packed (row<<17)|src
        }
    } else {
        for (int f = 0; f < nf; ++f) {
            int gbase = fp[f] * CH + fl0[f];
            for (int i = 0; i < flen[f]; ++i) {
                int p = pairs[gbase + i];
                int key = (((p & 0x1FFFF) >> CSH) << 7) | (p >> 17);
                int pos = atomicAdd(&lcnt[key], 1);
                col[pos] = p;
            }
        }
    }
}

// ---------------- precision prep ----------------

__global__ void wt_kernel(const float* __restrict__ W1, unsigned short* __restrict__ W1T,
                          const float* __restrict__ W2, unsigned short* __restrict__ W2T) {
    int k = blockIdx.x & (FD - 1);
    int n = threadIdx.x;
    if (blockIdx.x < FD) W1T[n * FD + k] = (unsigned short)bfr(W1[k * FD + n]);
    else                 W2T[n * FD + k] = (unsigned short)bfr(W2[k * FD + n]);
}

// ---------------- MFMA bf16 GEMM: C = bf16( dis[row] * (A @ W) ) ----------------

#define APAD 8
#define ASTR (FD + APAD)

template <bool A32>
__device__ void gemm_body(const void* __restrict__ Ap,
                          const unsigned short* __restrict__ WT,
                          const float* __restrict__ dis,
                          unsigned short* __restrict__ C, int M) {
    __shared__ unsigned short As[128 * ASTR];
    __shared__ unsigned short Bs[128 * ASTR];
    int tid = threadIdx.x;
    int lane = tid & 63;
    int wave = tid >> 6;
    int quad = lane >> 4;
    int l16 = lane & 15;
    int rowBase = blockIdx.x * 128;

    #pragma unroll
    for (int p = 0; p < 8; ++p) {
        int r = p * 16 + (tid >> 4);
        int cq = (tid & 15) * 8;
        int gr = rowBase + r;
        uint4 v = make_uint4(0u, 0u, 0u, 0u);
        if (A32) {
            if (gr < M) {
                const float* a = (const float*)Ap + (size_t)gr * FD + cq;
                float4 f0 = *(const float4*)a;
                float4 f1 = *(const float4*)(a + 4);
                v.x = bfr(f0.x) | (bfr(f0.y) << 16);
                v.y = bfr(f0.z) | (bfr(f0.w) << 16);
                v.z = bfr(f1.x) | (bfr(f1.y) << 16);
                v.w = bfr(f1.z) | (bfr(f1.w) << 16);
            }
        } else {
            if (gr < M) v = *(const uint4*)((const unsigned short*)Ap + (size_t)gr * FD + cq);
        }
        *(uint4*)&As[r * ASTR + cq] = v;
        *(uint4*)&Bs[r * ASTR + cq] = *(const uint4*)&WT[(size_t)r * FD + cq];
    }
    __syncthreads();

    int m0 = wave * 32;
    f32x4 acc[2][8] = {};
    #pragma unroll
    for (int kt = 0; kt < 4; ++kt) {
        int ko = kt * 32 + quad * 8;
        bf16x8 a0 = *(bf16x8*)&As[(m0 + l16) * ASTR + ko];
        bf16x8 a1 = *(bf16x8*)&As[(m0 + 16 + l16) * ASTR + ko];
        #pragma unroll
        for (int n = 0; n < 8; ++n) {
            bf16x8 b = *(bf16x8*)&Bs[(n * 16 + l16) * ASTR + ko];
            acc[0][n] = __builtin_amdgcn_mfma_f32_16x16x32_bf16(a0, b, acc[0][n], 0, 0, 0);
            acc[1][n] = __builtin_amdgcn_mfma_f32_16x16x32_bf16(a1, b, acc[1][n], 0, 0, 0);
        }
    }

    #pragma unroll
    for (int ms = 0; ms < 2; ++ms) {
        #pragma unroll
        for (int r = 0; r < 4; ++r) {
            int grow = rowBase + m0 + ms * 16 + quad * 4 + r;
            if (grow < M) {
                float dv = dis[grow];
                #pragma unroll
                for (int n = 0; n < 8; ++n) {
                    C[(size_t)grow * FD + n * 16 + l16] =
                        (unsigned short)bfr(dv * acc[ms][n][r]);
                }
            }
        }
    }
}

__global__ __launch_bounds__(256) void gemm_mfma_f32(
        const float* __restrict__ A, const unsigned short* __restrict__ WT,
        const float* __restrict__ dis, unsigned short* __restrict__ C, int M) {
    gemm_body<true>(A, WT, dis, C, M);
}

__global__ __launch_bounds__(256) void gemm_mfma_bf16(
        const unsigned short* __restrict__ A, const unsigned short* __restrict__ WT,
        const float* __restrict__ dis, unsigned short* __restrict__ C, int M) {
    gemm_body<false>(A, WT, dis, C, M);
}

// ---------------- CSR aggregation + bias + ReLU ----------------
// R18: bucket-parallel LDS accumulation. Block b owns bucket b (128 dst rows);
// accX/accY[128][64] in LDS (64 KB, stride-4 planes -> conflict-free).
// Each wave streams strided 16-edge batches of the bucket's chunk-ordered
// edge list: 16 broadcast col loads -> 16 independent h gathers (MLP=16) ->
// 2 fire-and-forget LDS atomicAdds per edge. No per-stream register state,
// no loop-carried memory dependency. All 391 blocks co-resident (2/CU),
// sweeping src chunks together -> ~2 MB live gather window per XCD.

__global__ __launch_bounds__(256) void agg_kernel(
        const unsigned* __restrict__ h, const float* __restrict__ dis,
        const int* __restrict__ bbase, const int* __restrict__ col,
        const float2* __restrict__ bias, void* __restrict__ out,
        int N, int obf) {
    __shared__ float accX[128][64];   // 32 KB
    __shared__ float accY[128][64];   // 32 KB
    int b = blockIdx.x;
    int t = threadIdx.x & 63;
    int w = threadIdx.x >> 6;

    #pragma unroll
    for (int r = 0; r < 32; ++r) {
        accX[w * 32 + r][t] = 0.0f;
        accY[w * 32 + r][t] = 0.0f;
    }
    __syncthreads();

    int beg = __builtin_amdgcn_readfirstlane(bbase[b]);
    int end = __builtin_amdgcn_readfirstlane(bbase[b + 1]);

    for (int e0 = beg + w * 16; e0 < end; e0 += 64) {
        int pk[16];
        #pragma unroll
        for (int i = 0; i < 16; ++i) {
            int e = e0 + i;
            pk[i] = (e < end) ? col[e] : -1;
        }
        unsigned q[16];
        #pragma unroll
        for (int i = 0; i < 16; ++i)
            if (pk[i] >= 0) q[i] = h[(size_t)(pk[i] & 0x1FFFF) * 64 + t];
        #pragma unroll
        for (int i = 0; i < 16; ++i)
            if (pk[i] >= 0) {
                int r = __builtin_amdgcn_readfirstlane(pk[i]) >> 17;
                atomicAdd(&accX[r][t], uplo(q[i]));
                atomicAdd(&accY[r][t], uphi(q[i]));
            }
    }
    __syncthreads();

    int nbase = b << BSH;
    float2 bb = bias[t];
    #pragma unroll
    for (int rr = 0; rr < 32; ++rr) {
        int r = w * 32 + rr;
        int v = nbase + r;
        if (v < N) {
            float dv = dis[v];
            size_t vb = (size_t)v * 64 + t;
            unsigned hp = h[vb];               // self term h'[v]
            float rx = fmaxf(fmaf(dv, accX[r][t] + uplo(hp), bb.x), 0.0f);
            float ry = fmaxf(fmaf(dv, accY[r][t] + uphi(hp), bb.y), 0.0f);
            if (obf) ((unsigned*)out)[vb] = bfr(rx) | (bfr(ry) << 16);
            else     ((float2*)out)[vb] = make_float2(rx, ry);
        }
    }
}

// ---------------- launch ----------------

extern "C" void kernel_launch(void* const* d_in, const int* in_sizes, int n_in,
                              void* d_out, int out_size, void* d_ws, size_t ws_size,
                              hipStream_t stream) {
    const float* x  = (const float*)d_in[0];
    const int*   ei = (const int*)d_in[1];   // [2, E] int32
    const float* W1 = (const float*)d_in[2];
    const float* b1 = (const float*)d_in[3];
    const float* W2 = (const float*)d_in[4];
    const float* b2 = (const float*)d_in[5];

    int N = in_sizes[0] / FD;
    int E = in_sizes[1] / 2;
    const int* src = ei;
    const int* dst = ei + E;
    int K = (N + (1 << BSH) - 1) >> BSH;     // buckets (<= 512 assumed)
    int PB = (E + CH - 1) / CH;              // partition blocks

    char* base = (char*)d_ws;
    size_t off = 0;
    auto align256 = [](size_t v) { return (v + 255) & ~(size_t)255; };
    float*          dis   = (float*)(base + off);          off += align256((size_t)N * 4);
    int*            total = (int*)(base + off);            off += align256(512 * 4);
    int*            bbase = (int*)(base + off);            off += align256(513 * 4);
    unsigned short* w1t   = (unsigned short*)(base + off); off += align256((size_t)FD * FD * 2);
    unsigned short* w2t   = (unsigned short*)(base + off); off += align256((size_t)FD * FD * 2);
    int*            col   = (int*)(base + off);            off += align256((size_t)E * 4);
    unsigned short* hbuf  = (unsigned short*)(base + off); off += align256((size_t)N * FD * 2);
    unsigned short* z1    = (unsigned short*)(base + off); off += align256((size_t)N * FD * 2);
    int*            pairs = (int*)(base + off);            off += align256((size_t)E * 4);
    int*            lstartG = (int*)hbuf;   // overlay: dead before gemm1 writes hbuf
    int*            lstartT = (int*)z1;     // overlay: dead before agg1 writes z1
    (void)ws_size; (void)n_in; (void)out_size;

    (void)hipMemsetAsync(total, 0, 512 * 4, stream);
    partition_kernel<<<PB, 256, 0, stream>>>(src, dst, lstartG, total, pairs, E, K);
    totscan_kernel  <<<1, 512, 0, stream>>>(total, bbase, K, E);
    dim3 trb(32, 8);
    dim3 trg((K + 1 + 31) / 32, (PB + 31) / 32);
    tr_kernel       <<<trg, trb, 0, stream>>>(lstartG, lstartT, PB, K + 1);
    build_kernel    <<<K, 256, 0, stream>>>(pairs, lstartT, bbase, dis, col, N, PB, K);

    wt_kernel<<<2 * FD, FD, 0, stream>>>(W1, w1t, W2, w2t);

    int gemmGrid = (N + 127) / 128;

    gemm_mfma_f32 <<<gemmGrid, 256, 0, stream>>>(x, w1t, dis, hbuf, N);
    agg_kernel<<<K, 256, 0, stream>>>((const unsigned*)hbuf, dis, bbase, col,
                                      (const float2*)b1, z1, N, 1);
    gemm_mfma_bf16<<<gemmGrid, 256, 0, stream>>>(z1, w2t, dis, hbuf, N);
    agg_kernel<<<K, 256, 0, stream>>>((const unsigned*)hbuf, dis, bbase, col,
                                      (const float2*)b2, d_out, N, 0);
}

// Round 7
// 256.980 us; speedup vs baseline: 11.2640x; 11.2640x over previous
//
#include <hip/hip_runtime.h>

#define FD 128      // feature dim (both layers)
#define BSH 7       // log2(nodes per bucket) = 128 nodes/bucket
#define CH 2048     // edges per partition block (782 blocks -> ~3 blocks/CU rounds)
#define CHT 8       // edges per thread (CH / 256)
#define KMAX 512    // max buckets
#define SCAP 8192   // build_kernel LDS edge stage (mean bucket = 4092, max ~4400)
// packed pair: (local_dst << 17) | src   -- requires N <= 131072

typedef __attribute__((ext_vector_type(8))) short bf16x8;
typedef __attribute__((ext_vector_type(4))) float f32x4;

__device__ inline unsigned bfr(float f) {   // fp32 -> bf16 bits, round-nearest-even
    unsigned u = __float_as_uint(f);
    return (u + 0x7FFF + ((u >> 16) & 1)) >> 16;
}
__device__ inline float uplo(unsigned p) { return __uint_as_float(p << 16); }
__device__ inline float uphi(unsigned p) { return __uint_as_float(p & 0xFFFF0000u); }

// ---------------- CSR build ----------------
// R19 = the round-0 proven build chain, verbatim (258 us total, agg 48.6 us).
// R12 scheme: each partition block multi-splits its CH-edge chunk in LDS and
// writes it back SEQUENTIALLY (bucket-sorted within the chunk) -> 1.0x write
// density with zero cross-block line sharing, independent of XCD placement.

__global__ __launch_bounds__(256) void partition_kernel(
        const int* __restrict__ src, const int* __restrict__ dst,
        int* __restrict__ lstartG, int* __restrict__ total,
        int* __restrict__ pairs, int E, int K) {
    __shared__ int lcnt[KMAX];     // counts, then scatter cursor
    __shared__ int lstart[KMAX];   // local exclusive prefix
    __shared__ int sm[256];
    __shared__ int staged[CH];
    int t = threadIdx.x;
    int base = blockIdx.x * CH;
    int n = min(CH, E - base);

    lcnt[t] = 0; lcnt[t + 256] = 0;
    __syncthreads();

    int pk[CHT]; int bn[CHT];
    #pragma unroll
    for (int j = 0; j < CHT; ++j) {
        int i = t + j * 256;
        bn[j] = -1;
        if (i < n) {
            int d = dst[base + i];
            int s = src[base + i];
            bn[j] = d >> BSH;
            pk[j] = ((d & ((1 << BSH) - 1)) << 17) | s;
            atomicAdd(&lcnt[bn[j]], 1);
        }
    }
    __syncthreads();

    // exclusive scan of 512 bins, 2 consecutive bins per thread
    int c0 = lcnt[2 * t], c1 = lcnt[2 * t + 1];
    int s2 = c0 + c1;
    sm[t] = s2;
    __syncthreads();
    for (int off = 1; off < 256; off <<= 1) {
        int add = (t >= off) ? sm[t - off] : 0;
        __syncthreads();
        sm[t] += add;
        __syncthreads();
    }
    int ex = sm[t] - s2;
    lstart[2 * t] = ex;     lstart[2 * t + 1] = ex + c0;
    lcnt[2 * t]   = ex;     lcnt[2 * t + 1]   = ex + c0;   // cursor
    __syncthreads();

    // scatter chunk into staged[], sorted by bucket
    #pragma unroll
    for (int j = 0; j < CHT; ++j) {
        if (bn[j] >= 0) {
            int pos = atomicAdd(&lcnt[bn[j]], 1);
            staged[pos] = pk[j];
        }
    }
    __syncthreads();

    // sequential coalesced copy-out: this block owns pairs[base .. base+n)
    for (int i = t; i < n; i += 256)
        pairs[base + i] = staged[i];

    // per-block bucket boundaries + bucket totals
    size_t lrow = (size_t)blockIdx.x * (K + 1);
    for (int b = t; b < K; b += 256) {
        lstartG[lrow + b] = lstart[b];
        int c = lcnt[b] - lstart[b];
        if (c) atomicAdd(&total[b], c);
    }
    if (t == 0) lstartG[lrow + K] = n;
}

// exclusive scan of K bucket totals -> bbase; also rp[N]=E
__global__ __launch_bounds__(512) void totscan_kernel(
        const int* __restrict__ total, int* __restrict__ bbase,
        int* __restrict__ rp, int K, int E, int N) {
    __shared__ int sm[512];
    int t = threadIdx.x;
    int v = (t < K) ? total[t] : 0;
    sm[t] = v;
    __syncthreads();
    for (int off = 1; off < 512; off <<= 1) {
        int add = (t >= off) ? sm[t - off] : 0;
        __syncthreads();
        sm[t] += add;
        __syncthreads();
    }
    if (t < K) bbase[t] = sm[t] - v;
    if (t == 0) { bbase[K] = E; rp[N] = E; }
}

// Per-bucket: gather this bucket's fragments (thread-per-fragment) into LDS,
// then count + scan + scatter; writes rp/dis/col. col writes confined to the
// bucket's contiguous region -> dense.
__global__ __launch_bounds__(256) void build_kernel(
        const int* __restrict__ pairs, const int* __restrict__ lstartG,
        const int* __restrict__ bbase, int* __restrict__ rp,
        float* __restrict__ dis, int* __restrict__ col, int N, int PB, int K) {
    __shared__ int staged[SCAP];
    __shared__ int lcnt[1 << BSH];
    __shared__ int lsum[1 << BSH];
    __shared__ int lbase[1 << BSH];
    __shared__ int sm[256];
    int b = blockIdx.x;
    int t = threadIdx.x;
    int nbase = b << BSH;
    int nn = min(1 << BSH, N - nbase);
    int beg = bbase[b];
    int cnt = bbase[b + 1] - beg;

    // fragment descriptors for this thread (p = t, t+256, ...; <= 4)
    int fp[4], fl0[4], flen[4];
    int nf = 0, mysum = 0;
    for (int p = t; p < PB; p += 256) {
        size_t lrow = (size_t)p * (K + 1);
        int l0 = lstartG[lrow + b];
        int l1 = lstartG[lrow + b + 1];
        fp[nf] = p; fl0[nf] = l0; flen[nf] = l1 - l0;
        mysum += l1 - l0;
        ++nf;
    }
    // exclusive scan of per-thread sums -> dest offsets in staged
    sm[t] = mysum;
    __syncthreads();
    for (int off = 1; off < 256; off <<= 1) {
        int add = (t >= off) ? sm[t - off] : 0;
        __syncthreads();
        sm[t] += add;
        __syncthreads();
    }
    int o = sm[t] - mysum;

    if (t < 128) lcnt[t] = 0;

    if (cnt <= SCAP) {   // fast path (always, for Poisson buckets)
        for (int f = 0; f < nf; ++f) {
            int gbase = fp[f] * CH + fl0[f];
            for (int i = 0; i < flen[f]; ++i) staged[o + i] = pairs[gbase + i];
            o += flen[f];
        }
        __syncthreads();
        for (int i = t; i < cnt; i += 256) atomicAdd(&lcnt[staged[i] >> 17], 1);
    } else {             // overflow fallback: count directly from global
        __syncthreads();
        for (int f = 0; f < nf; ++f) {
            int gbase = fp[f] * CH + fl0[f];
            for (int i = 0; i < flen[f]; ++i)
                atomicAdd(&lcnt[pairs[gbase + i] >> 17], 1);
        }
    }
    __syncthreads();

    if (t < 128) lsum[t] = lcnt[t];
    __syncthreads();
    for (int off = 1; off < 128; off <<= 1) {
        int add = (t < 128 && t >= off) ? lsum[t - off] : 0;
        __syncthreads();
        if (t < 128) lsum[t] += add;
        __syncthreads();
    }
    if (t < 128) {
        int excl = beg + lsum[t] - lcnt[t];
        lbase[t] = excl;
        if (t < nn) {
            rp[nbase + t] = excl;
            dis[nbase + t] = rsqrtf((float)(lcnt[t] + 1));  // deg incl. self-loop
        }
    }
    __syncthreads();
    if (t < 128) lcnt[t] = lbase[t];   // reuse as cursor
    __syncthreads();

    if (cnt <= SCAP) {
        for (int i = t; i < cnt; i += 256) {
            int p = staged[i];
            int pos = atomicAdd(&lcnt[p >> 17], 1);
            col[pos] = p & 0x1FFFF;
        }
    } else {
        for (int f = 0; f < nf; ++f) {
            int gbase = fp[f] * CH + fl0[f];
            for (int i = 0; i < flen[f]; ++i) {
                int p = pairs[gbase + i];
                int pos = atomicAdd(&lcnt[p >> 17], 1);
                col[pos] = p & 0x1FFFF;
            }
        }
    }
}

// ---------------- precision prep ----------------

// W[k][n] fp32 -> WT[n][k] bf16, both weights in one launch (gridDim.x = 2*FD)
__global__ void wt_kernel(const float* __restrict__ W1, unsigned short* __restrict__ W1T,
                          const float* __restrict__ W2, unsigned short* __restrict__ W2T) {
    int k = blockIdx.x & (FD - 1);
    int n = threadIdx.x;
    if (blockIdx.x < FD) W1T[n * FD + k] = (unsigned short)bfr(W1[k * FD + n]);
    else                 W2T[n * FD + k] = (unsigned short)bfr(W2[k * FD + n]);
}

// ---------------- MFMA bf16 GEMM: C = bf16( dis[row] * (A @ W) ) ----------------
// R19 lean variant: only B (weights) staged in LDS (34.8 KB -> 4 blocks/CU,
// 2x occupancy vs round-0's 69.6 KB A+B staging). A fragments are loaded
// DIRECTLY from global: lane l16 = row, quad = k-octet, so lanes (l16, quad
// 0..3) cover row l16's contiguous 64 B -> clean 64 B sectors, each A row
// read exactly once per kt by its owning wave. One barrier instead of two.
// A32 path converts fp32->bf16 in-register (same bfr count as staging did).

#define APAD 8
#define ASTR (FD + APAD)

template <bool A32>
__device__ void gemm_body(const void* __restrict__ Ap,
                          const unsigned short* __restrict__ WT,
                          const float* __restrict__ dis,
                          unsigned short* __restrict__ C, int M) {
    __shared__ unsigned short Bs[128 * ASTR];
    int tid = threadIdx.x;
    int lane = tid & 63;
    int wave = tid >> 6;
    int quad = lane >> 4;
    int l16 = lane & 15;
    int rowBase = blockIdx.x * 128;

    #pragma unroll
    for (int p = 0; p < 8; ++p) {
        int r = p * 16 + (tid >> 4);
        int cq = (tid & 15) * 8;
        *(uint4*)&Bs[r * ASTR + cq] = *(const uint4*)&WT[(size_t)r * FD + cq];
    }
    __syncthreads();

    int m0 = wave * 32;
    int r0 = rowBase + m0 + l16;        // a0 fragment row
    int r1 = r0 + 16;                   // a1 fragment row
    f32x4 acc[2][8] = {};
    #pragma unroll
    for (int kt = 0; kt < 4; ++kt) {
        int ko = kt * 32 + quad * 8;
        uint4 va = make_uint4(0u, 0u, 0u, 0u);
        uint4 vb = make_uint4(0u, 0u, 0u, 0u);
        if (A32) {
            const float* A = (const float*)Ap;
            if (r0 < M) {
                const float* a = A + (size_t)r0 * FD + ko;
                float4 f0 = *(const float4*)a;
                float4 f1 = *(const float4*)(a + 4);
                va.x = bfr(f0.x) | (bfr(f0.y) << 16);
                va.y = bfr(f0.z) | (bfr(f0.w) << 16);
                va.z = bfr(f1.x) | (bfr(f1.y) << 16);
                va.w = bfr(f1.z) | (bfr(f1.w) << 16);
            }
            if (r1 < M) {
                const float* a = A + (size_t)r1 * FD + ko;
                float4 f0 = *(const float4*)a;
                float4 f1 = *(const float4*)(a + 4);
                vb.x = bfr(f0.x) | (bfr(f0.y) << 16);
                vb.y = bfr(f0.z) | (bfr(f0.w) << 16);
                vb.z = bfr(f1.x) | (bfr(f1.y) << 16);
                vb.w = bfr(f1.z) | (bfr(f1.w) << 16);
            }
        } else {
            const unsigned short* A = (const unsigned short*)Ap;
            if (r0 < M) va = *(const uint4*)(A + (size_t)r0 * FD + ko);
            if (r1 < M) vb = *(const uint4*)(A + (size_t)r1 * FD + ko);
        }
        bf16x8 a0 = *(bf16x8*)&va;
        bf16x8 a1 = *(bf16x8*)&vb;
        #pragma unroll
        for (int n = 0; n < 8; ++n) {
            bf16x8 b = *(bf16x8*)&Bs[(n * 16 + l16) * ASTR + ko];
            acc[0][n] = __builtin_amdgcn_mfma_f32_16x16x32_bf16(a0, b, acc[0][n], 0, 0, 0);
            acc[1][n] = __builtin_amdgcn_mfma_f32_16x16x32_bf16(a1, b, acc[1][n], 0, 0, 0);
        }
    }

    #pragma unroll
    for (int ms = 0; ms < 2; ++ms) {
        #pragma unroll
        for (int r = 0; r < 4; ++r) {
            int grow = rowBase + m0 + ms * 16 + quad * 4 + r;
            if (grow < M) {
                float dv = dis[grow];
                #pragma unroll
                for (int n = 0; n < 8; ++n) {
                    C[(size_t)grow * FD + n * 16 + l16] =
                        (unsigned short)bfr(dv * acc[ms][n][r]);
                }
            }
        }
    }
}

__global__ __launch_bounds__(256) void gemm_mfma_f32(
        const float* __restrict__ A, const unsigned short* __restrict__ WT,
        const float* __restrict__ dis, unsigned short* __restrict__ C, int M) {
    gemm_body<true>(A, WT, dis, C, M);
}

__global__ __launch_bounds__(256) void gemm_mfma_bf16(
        const unsigned short* __restrict__ A, const unsigned short* __restrict__ WT,
        const float* __restrict__ dis, unsigned short* __restrict__ C, int M) {
    gemm_body<false>(A, WT, dis, C, M);
}

// ---------------- CSR aggregation + bias + ReLU ----------------
// Round-0 proven form (48.6 us, 67% occupancy, 28 VGPR): h' pre-scaled by
// dis, stored bf16 row-major (2 per uint). One node per wave, lane t =
// features [2t,2t+1], plain cached loads, 16 edges in flight.
// out[v] = relu(dis[v]*(h'[v]+sum_u h'[u]) + b).
// obf=1: write packed bf16 (z1, feeds gemm2); obf=0: write fp32 (final out).

__global__ __launch_bounds__(256) void agg_kernel(
        const unsigned* __restrict__ h, const float* __restrict__ dis,
        const int* __restrict__ rp, const int* __restrict__ col,
        const float2* __restrict__ bias, void* __restrict__ out, int N, int obf) {
    int v = blockIdx.x * 4 + threadIdx.y;          // blockDim = (64, 4): wave per node
    v = __builtin_amdgcn_readfirstlane(v);         // wave-uniform -> scalar rp/col loads
    if (v >= N) return;
    int t = threadIdx.x;                           // 0..63
    float dv = dis[v];
    size_t vb = (size_t)v * 64 + t;
    unsigned hp = h[vb];                           // self term h'[v]
    float2 acc;
    acc.x = uplo(hp); acc.y = uphi(hp);
    int e = rp[v];
    int end = rp[v + 1];

    for (; e + 16 <= end; e += 16) {
        int u[16];
        #pragma unroll
        for (int j = 0; j < 16; ++j) u[j] = col[e + j];   // wave-uniform scalar loads
        unsigned p[16];
        #pragma unroll
        for (int j = 0; j < 16; ++j) p[j] = h[(size_t)u[j] * 64 + t];
        #pragma unroll
        for (int j = 0; j < 16; ++j) {
            acc.x += uplo(p[j]); acc.y += uphi(p[j]);
        }
    }
    for (; e + 4 <= end; e += 4) {
        int u0 = col[e], u1 = col[e + 1], u2 = col[e + 2], u3 = col[e + 3];
        unsigned p0 = h[(size_t)u0 * 64 + t];
        unsigned p1 = h[(size_t)u1 * 64 + t];
        unsigned p2 = h[(size_t)u2 * 64 + t];
        unsigned p3 = h[(size_t)u3 * 64 + t];
        acc.x += uplo(p0); acc.y += uphi(p0);
        acc.x += uplo(p1); acc.y += uphi(p1);
        acc.x += uplo(p2); acc.y += uphi(p2);
        acc.x += uplo(p3); acc.y += uphi(p3);
    }
    for (; e < end; ++e) {
        unsigned p = h[(size_t)col[e] * 64 + t];
        acc.x += uplo(p); acc.y += uphi(p);
    }

    float2 bb = bias[t];
    float2 r;
    r.x = fmaxf(fmaf(dv, acc.x, bb.x), 0.0f);
    r.y = fmaxf(fmaf(dv, acc.y, bb.y), 0.0f);
    if (obf) {
        ((unsigned*)out)[vb] = bfr(r.x) | (bfr(r.y) << 16);
    } else {
        ((float2*)out)[vb] = r;
    }
}

// ---------------- launch ----------------

extern "C" void kernel_launch(void* const* d_in, const int* in_sizes, int n_in,
                              void* d_out, int out_size, void* d_ws, size_t ws_size,
                              hipStream_t stream) {
    const float* x  = (const float*)d_in[0];
    const int*   ei = (const int*)d_in[1];   // [2, E] int32
    const float* W1 = (const float*)d_in[2];
    const float* b1 = (const float*)d_in[3];
    const float* W2 = (const float*)d_in[4];
    const float* b2 = (const float*)d_in[5];

    int N = in_sizes[0] / FD;
    int E = in_sizes[1] / 2;
    const int* src = ei;
    const int* dst = ei + E;
    int K = (N + (1 << BSH) - 1) >> BSH;     // buckets (<= 512 assumed)
    int PB = (E + CH - 1) / CH;              // partition blocks

    char* base = (char*)d_ws;
    size_t off = 0;
    auto align256 = [](size_t v) { return (v + 255) & ~(size_t)255; };
    int*            rp    = (int*)(base + off);            off += align256((size_t)(N + 1) * 4);
    float*          dis   = (float*)(base + off);          off += align256((size_t)N * 4);
    int*            total = (int*)(base + off);            off += align256(512 * 4);
    int*            bbase = (int*)(base + off);            off += align256(513 * 4);
    unsigned short* w1t   = (unsigned short*)(base + off); off += align256((size_t)FD * FD * 2);
    unsigned short* w2t   = (unsigned short*)(base + off); off += align256((size_t)FD * FD * 2);
    int*            col   = (int*)(base + off);            off += align256((size_t)E * 4);
    unsigned short* hbuf  = (unsigned short*)(base + off); off += align256((size_t)N * FD * 2);
    unsigned short* z1    = (unsigned short*)(base + off); off += align256((size_t)N * FD * 2);
    int*            pairs = (int*)(base + off);            off += align256((size_t)E * 4);
    int*            lstartG = (int*)hbuf;   // overlay: dead until build completes,
                                            // gemm1 (first hbuf writer) runs after.
    (void)ws_size; (void)n_in; (void)out_size;

    (void)hipMemsetAsync(total, 0, 512 * 4, stream);
    partition_kernel<<<PB, 256, 0, stream>>>(src, dst, lstartG, total, pairs, E, K);
    totscan_kernel  <<<1, 512, 0, stream>>>(total, bbase, rp, K, E, N);
    build_kernel    <<<K, 256, 0, stream>>>(pairs, lstartG, bbase, rp, dis, col, N, PB, K);

    wt_kernel<<<2 * FD, FD, 0, stream>>>(W1, w1t, W2, w2t);

    dim3 aggBlk(64, 4);
    int aggGrid = (N + 3) / 4;
    int gemmGrid = (N + 127) / 128;

    gemm_mfma_f32 <<<gemmGrid, 256, 0, stream>>>(x, w1t, dis, hbuf, N);
    agg_kernel<<<aggGrid, aggBlk, 0, stream>>>((const unsigned*)hbuf, dis, rp, col,
                                               (const float2*)b1, z1, N, 1);
    gemm_mfma_bf16<<<gemmGrid, 256, 0, stream>>>(z1, w2t, dis, hbuf, N);
    agg_kernel<<<aggGrid, aggBlk, 0, stream>>>((const unsigned*)hbuf, dis, rp, col,
                                               (const float2*)b2, d_out, N, 0);
}

// Round 8
// 248.428 us; speedup vs baseline: 11.6517x; 1.0344x over previous
//
#include <hip/hip_runtime.h>

#define FD 128      // feature dim (both layers)
#define BSH 7       // log2(nodes per bucket) = 128 nodes/bucket
#define CH 4096     // edges per partition block (391 blocks, R8: was 2048)
#define CHT 16      // edges per thread (CH / 256)
#define KMAX 512    // max buckets
#define SCAP 8192   // build_kernel LDS edge stage (mean bucket = 4092, max ~4400)
// packed pair: (local_dst << 17) | src   -- requires N <= 131072

typedef __attribute__((ext_vector_type(8))) short bf16x8;
typedef __attribute__((ext_vector_type(4))) float f32x4;

__device__ inline unsigned bfr(float f) {   // fp32 -> bf16 bits, round-nearest-even
    unsigned u = __float_as_uint(f);
    return (u + 0x7FFF + ((u >> 16) & 1)) >> 16;
}
__device__ inline float uplo(unsigned p) { return __uint_as_float(p << 16); }
__device__ inline float uphi(unsigned p) { return __uint_as_float(p & 0xFFFF0000u); }

// ---------------- CSR build ----------------
// R8 chain: partition multi-split (1.0x write density) with CH=4096 (2x edge
// amortization of per-block scan/flush); tr_kernel transposes lstart so build
// reads descriptors coalesced; build fuses the bin-count into the staging
// pass and uses per-wave histogram planes ([bin][wave], 512 bins) to cut LDS
// atomic contention ~4x. agg/gemm are the round-0-proven forms, untouched.

__global__ __launch_bounds__(256) void partition_kernel(
        const int* __restrict__ src, const int* __restrict__ dst,
        int* __restrict__ lstartG, int* __restrict__ total,
        int* __restrict__ pairs, int E, int K) {
    __shared__ int lcnt[KMAX];     // counts, then scatter cursor
    __shared__ int lstart[KMAX];   // local exclusive prefix
    __shared__ int sm[256];
    __shared__ int staged[CH];
    int t = threadIdx.x;
    int base = blockIdx.x * CH;
    int n = min(CH, E - base);

    lcnt[t] = 0; lcnt[t + 256] = 0;
    __syncthreads();

    int pk[CHT]; int bn[CHT];
    #pragma unroll
    for (int j = 0; j < CHT; ++j) {
        int i = t + j * 256;
        bn[j] = -1;
        if (i < n) {
            int d = dst[base + i];
            int s = src[base + i];
            bn[j] = d >> BSH;
            pk[j] = ((d & ((1 << BSH) - 1)) << 17) | s;
            atomicAdd(&lcnt[bn[j]], 1);
        }
    }
    __syncthreads();

    // exclusive scan of 512 bins, 2 consecutive bins per thread
    int c0 = lcnt[2 * t], c1 = lcnt[2 * t + 1];
    int s2 = c0 + c1;
    sm[t] = s2;
    __syncthreads();
    for (int off = 1; off < 256; off <<= 1) {
        int add = (t >= off) ? sm[t - off] : 0;
        __syncthreads();
        sm[t] += add;
        __syncthreads();
    }
    int ex = sm[t] - s2;
    lstart[2 * t] = ex;     lstart[2 * t + 1] = ex + c0;
    lcnt[2 * t]   = ex;     lcnt[2 * t + 1]   = ex + c0;   // cursor
    __syncthreads();

    // scatter chunk into staged[], sorted by bucket
    #pragma unroll
    for (int j = 0; j < CHT; ++j) {
        if (bn[j] >= 0) {
            int pos = atomicAdd(&lcnt[bn[j]], 1);
            staged[pos] = pk[j];
        }
    }
    __syncthreads();

    // sequential coalesced copy-out: this block owns pairs[base .. base+n)
    for (int i = t; i < n; i += 256)
        pairs[base + i] = staged[i];

    // per-block bucket boundaries + bucket totals
    size_t lrow = (size_t)blockIdx.x * (K + 1);
    for (int b = t; b < K; b += 256) {
        lstartG[lrow + b] = lstart[b];
        int c = lcnt[b] - lstart[b];
        if (c) atomicAdd(&total[b], c);
    }
    if (t == 0) lstartG[lrow + K] = n;
}

// exclusive scan of K bucket totals -> bbase; also rp[N]=E
__global__ __launch_bounds__(512) void totscan_kernel(
        const int* __restrict__ total, int* __restrict__ bbase,
        int* __restrict__ rp, int K, int E, int N) {
    __shared__ int sm[512];
    int t = threadIdx.x;
    int v = (t < K) ? total[t] : 0;
    sm[t] = v;
    __syncthreads();
    for (int off = 1; off < 512; off <<= 1) {
        int add = (t >= off) ? sm[t - off] : 0;
        __syncthreads();
        sm[t] += add;
        __syncthreads();
    }
    if (t < K) bbase[t] = sm[t] - v;
    if (t == 0) { bbase[K] = E; rp[N] = E; }
}

// transpose A[R][C] -> B[C][R]  (lstartG [PB][K+1] -> lstartT [K+1][PB])
// so build's per-fragment descriptor reads are coalesced.
__global__ __launch_bounds__(256) void tr_kernel(
        const int* __restrict__ A, int* __restrict__ B, int R, int C) {
    __shared__ int tile[32][33];
    int c0 = blockIdx.x * 32, r0 = blockIdx.y * 32;
    int tx = threadIdx.x, ty = threadIdx.y;   // block (32, 8)
    for (int i = ty; i < 32; i += 8) {
        int r = r0 + i, c = c0 + tx;
        if (r < R && c < C) tile[i][tx] = A[(size_t)r * C + c];
    }
    __syncthreads();
    for (int i = ty; i < 32; i += 8) {
        int c = c0 + i, r = r0 + tx;
        if (c < C && r < R) B[(size_t)c * R + r] = tile[tx][i];
    }
}

// Per-bucket: stage fragments into LDS with FUSED per-wave bin count,
// 512-entry scan ([bin][wave] bin-major), then scatter with per-wave cursors.
// Count plane == scatter plane by construction (same thread walks its own
// staged range in both passes).
__global__ __launch_bounds__(256) void build_kernel(
        const int* __restrict__ pairs, const int* __restrict__ lstartT,
        const int* __restrict__ bbase, int* __restrict__ rp,
        float* __restrict__ dis, int* __restrict__ col, int N, int PB, int K) {
    __shared__ int staged[SCAP];
    __shared__ int lcnt[512];    // [bin*4+wave] counts, then absolute cursor
    __shared__ int pref[512];    // exclusive prefix (bucket-local)
    __shared__ int sm[256];
    int b = blockIdx.x;
    int t = threadIdx.x;
    int wv = t >> 6;
    int nbase = b << BSH;
    int nn = min(1 << BSH, N - nbase);
    int beg = bbase[b];
    int cnt = bbase[b + 1] - beg;

    // fragment descriptors (coalesced reads from transposed lstart; nf <= 2)
    int fp[2], fl0[2], flen[2];
    int nf = 0, mysum = 0;
    for (int p = t; p < PB; p += 256) {
        int l0 = lstartT[(size_t)b * PB + p];
        int l1 = lstartT[(size_t)(b + 1) * PB + p];
        fp[nf] = p; fl0[nf] = l0; flen[nf] = l1 - l0;
        mysum += l1 - l0;
        ++nf;
    }
    // exclusive scan of per-thread sums -> dest offsets in staged
    sm[t] = mysum;
    __syncthreads();
    for (int off = 1; off < 256; off <<= 1) {
        int add = (t >= off) ? sm[t - off] : 0;
        __syncthreads();
        sm[t] += add;
        __syncthreads();
    }
    int o = sm[t] - mysum;

    lcnt[t] = 0; lcnt[t + 256] = 0;
    __syncthreads();

    if (cnt <= SCAP) {   // fast path (always, for Poisson buckets)
        int oo = o;
        for (int f = 0; f < nf; ++f) {
            int gbase = fp[f] * CH + fl0[f];
            for (int i = 0; i < flen[f]; ++i) {
                int p = pairs[gbase + i];
                staged[oo + i] = p;
                atomicAdd(&lcnt[((p >> 17) << 2) | wv], 1);   // fused count
            }
            oo += flen[f];
        }
    } else {             // overflow fallback: count directly from global
        for (int f = 0; f < nf; ++f) {
            int gbase = fp[f] * CH + fl0[f];
            for (int i = 0; i < flen[f]; ++i)
                atomicAdd(&lcnt[((pairs[gbase + i] >> 17) << 2) | wv], 1);
        }
    }
    __syncthreads();

    // exclusive scan of 512 entries (bin-major: bin*4+wave), 2 per thread
    int c0 = lcnt[2 * t], c1 = lcnt[2 * t + 1];
    int s2 = c0 + c1;
    sm[t] = s2;
    __syncthreads();
    for (int off = 1; off < 256; off <<= 1) {
        int add = (t >= off) ? sm[t - off] : 0;
        __syncthreads();
        sm[t] += add;
        __syncthreads();
    }
    int ex = sm[t] - s2;
    pref[2 * t] = ex;  pref[2 * t + 1] = ex + c0;
    __syncthreads();

    // rp/dis per row (row start = plane-0 prefix; deg = row-range length)
    if (t < 128 && t < nn) {
        int rs = pref[t << 2];
        int re = (t < 127) ? pref[(t + 1) << 2] : cnt;
        rp[nbase + t] = beg + rs;
        dis[nbase + t] = rsqrtf((float)(re - rs + 1));  // deg incl. self-loop
    }
    // cursors (absolute)
    lcnt[2 * t]     = beg + pref[2 * t];
    lcnt[2 * t + 1] = beg + pref[2 * t + 1];
    __syncthreads();

    if (cnt <= SCAP) {
        int oo = o;
        for (int f = 0; f < nf; ++f) {
            for (int i = 0; i < flen[f]; ++i) {
                int p = staged[oo + i];
                int pos = atomicAdd(&lcnt[((p >> 17) << 2) | wv], 1);
                col[pos] = p & 0x1FFFF;
            }
            oo += flen[f];
        }
    } else {
        for (int f = 0; f < nf; ++f) {
            int gbase = fp[f] * CH + fl0[f];
            for (int i = 0; i < flen[f]; ++i) {
                int p = pairs[gbase + i];
                int pos = atomicAdd(&lcnt[((p >> 17) << 2) | wv], 1);
                col[pos] = p & 0x1FFFF;
            }
        }
    }
}

// ---------------- precision prep ----------------

// W[k][n] fp32 -> WT[n][k] bf16, both weights in one launch (gridDim.x = 2*FD)
__global__ void wt_kernel(const float* __restrict__ W1, unsigned short* __restrict__ W1T,
                          const float* __restrict__ W2, unsigned short* __restrict__ W2T) {
    int k = blockIdx.x & (FD - 1);
    int n = threadIdx.x;
    if (blockIdx.x < FD) W1T[n * FD + k] = (unsigned short)bfr(W1[k * FD + n]);
    else                 W2T[n * FD + k] = (unsigned short)bfr(W2[k * FD + n]);
}

// ---------------- MFMA bf16 GEMM: C = bf16( dis[row] * (A @ W) ) ----------------
// R7-proven lean variant: only B staged in LDS; A fragments loaded directly
// from global (lane l16 = row, quad = k-octet -> clean 64 B sectors).

#define APAD 8
#define ASTR (FD + APAD)

template <bool A32>
__device__ void gemm_body(const void* __restrict__ Ap,
                          const unsigned short* __restrict__ WT,
                          const float* __restrict__ dis,
                          unsigned short* __restrict__ C, int M) {
    __shared__ unsigned short Bs[128 * ASTR];
    int tid = threadIdx.x;
    int lane = tid & 63;
    int wave = tid >> 6;
    int quad = lane >> 4;
    int l16 = lane & 15;
    int rowBase = blockIdx.x * 128;

    #pragma unroll
    for (int p = 0; p < 8; ++p) {
        int r = p * 16 + (tid >> 4);
        int cq = (tid & 15) * 8;
        *(uint4*)&Bs[r * ASTR + cq] = *(const uint4*)&WT[(size_t)r * FD + cq];
    }
    __syncthreads();

    int m0 = wave * 32;
    int r0 = rowBase + m0 + l16;        // a0 fragment row
    int r1 = r0 + 16;                   // a1 fragment row
    f32x4 acc[2][8] = {};
    #pragma unroll
    for (int kt = 0; kt < 4; ++kt) {
        int ko = kt * 32 + quad * 8;
        uint4 va = make_uint4(0u, 0u, 0u, 0u);
        uint4 vb = make_uint4(0u, 0u, 0u, 0u);
        if (A32) {
            const float* A = (const float*)Ap;
            if (r0 < M) {
                const float* a = A + (size_t)r0 * FD + ko;
                float4 f0 = *(const float4*)a;
                float4 f1 = *(const float4*)(a + 4);
                va.x = bfr(f0.x) | (bfr(f0.y) << 16);
                va.y = bfr(f0.z) | (bfr(f0.w) << 16);
                va.z = bfr(f1.x) | (bfr(f1.y) << 16);
                va.w = bfr(f1.z) | (bfr(f1.w) << 16);
            }
            if (r1 < M) {
                const float* a = A + (size_t)r1 * FD + ko;
                float4 f0 = *(const float4*)a;
                float4 f1 = *(const float4*)(a + 4);
                vb.x = bfr(f0.x) | (bfr(f0.y) << 16);
                vb.y = bfr(f0.z) | (bfr(f0.w) << 16);
                vb.z = bfr(f1.x) | (bfr(f1.y) << 16);
                vb.w = bfr(f1.z) | (bfr(f1.w) << 16);
            }
        } else {
            const unsigned short* A = (const unsigned short*)Ap;
            if (r0 < M) va = *(const uint4*)(A + (size_t)r0 * FD + ko);
            if (r1 < M) vb = *(const uint4*)(A + (size_t)r1 * FD + ko);
        }
        bf16x8 a0 = *(bf16x8*)&va;
        bf16x8 a1 = *(bf16x8*)&vb;
        #pragma unroll
        for (int n = 0; n < 8; ++n) {
            bf16x8 b = *(bf16x8*)&Bs[(n * 16 + l16) * ASTR + ko];
            acc[0][n] = __builtin_amdgcn_mfma_f32_16x16x32_bf16(a0, b, acc[0][n], 0, 0, 0);
            acc[1][n] = __builtin_amdgcn_mfma_f32_16x16x32_bf16(a1, b, acc[1][n], 0, 0, 0);
        }
    }

    #pragma unroll
    for (int ms = 0; ms < 2; ++ms) {
        #pragma unroll
        for (int r = 0; r < 4; ++r) {
            int grow = rowBase + m0 + ms * 16 + quad * 4 + r;
            if (grow < M) {
                float dv = dis[grow];
                #pragma unroll
                for (int n = 0; n < 8; ++n) {
                    C[(size_t)grow * FD + n * 16 + l16] =
                        (unsigned short)bfr(dv * acc[ms][n][r]);
                }
            }
        }
    }
}

__global__ __launch_bounds__(256) void gemm_mfma_f32(
        const float* __restrict__ A, const unsigned short* __restrict__ WT,
        const float* __restrict__ dis, unsigned short* __restrict__ C, int M) {
    gemm_body<true>(A, WT, dis, C, M);
}

__global__ __launch_bounds__(256) void gemm_mfma_bf16(
        const unsigned short* __restrict__ A, const unsigned short* __restrict__ WT,
        const float* __restrict__ dis, unsigned short* __restrict__ C, int M) {
    gemm_body<false>(A, WT, dis, C, M);
}

// ---------------- CSR aggregation + bias + ReLU ----------------
// Round-0 proven form (48.6 us, 67% occupancy, 28 VGPR) — UNCHANGED.

__global__ __launch_bounds__(256) void agg_kernel(
        const unsigned* __restrict__ h, const float* __restrict__ dis,
        const int* __restrict__ rp, const int* __restrict__ col,
        const float2* __restrict__ bias, void* __restrict__ out, int N, int obf) {
    int v = blockIdx.x * 4 + threadIdx.y;          // blockDim = (64, 4): wave per node
    v = __builtin_amdgcn_readfirstlane(v);         // wave-uniform -> scalar rp/col loads
    if (v >= N) return;
    int t = threadIdx.x;                           // 0..63
    float dv = dis[v];
    size_t vb = (size_t)v * 64 + t;
    unsigned hp = h[vb];                           // self term h'[v]
    float2 acc;
    acc.x = uplo(hp); acc.y = uphi(hp);
    int e = rp[v];
    int end = rp[v + 1];

    for (; e + 16 <= end; e += 16) {
        int u[16];
        #pragma unroll
        for (int j = 0; j < 16; ++j) u[j] = col[e + j];   // wave-uniform scalar loads
        unsigned p[16];
        #pragma unroll
        for (int j = 0; j < 16; ++j) p[j] = h[(size_t)u[j] * 64 + t];
        #pragma unroll
        for (int j = 0; j < 16; ++j) {
            acc.x += uplo(p[j]); acc.y += uphi(p[j]);
        }
    }
    for (; e + 4 <= end; e += 4) {
        int u0 = col[e], u1 = col[e + 1], u2 = col[e + 2], u3 = col[e + 3];
        unsigned p0 = h[(size_t)u0 * 64 + t];
        unsigned p1 = h[(size_t)u1 * 64 + t];
        unsigned p2 = h[(size_t)u2 * 64 + t];
        unsigned p3 = h[(size_t)u3 * 64 + t];
        acc.x += uplo(p0); acc.y += uphi(p0);
        acc.x += uplo(p1); acc.y += uphi(p1);
        acc.x += uplo(p2); acc.y += uphi(p2);
        acc.x += uplo(p3); acc.y += uphi(p3);
    }
    for (; e < end; ++e) {
        unsigned p = h[(size_t)col[e] * 64 + t];
        acc.x += uplo(p); acc.y += uphi(p);
    }

    float2 bb = bias[t];
    float2 r;
    r.x = fmaxf(fmaf(dv, acc.x, bb.x), 0.0f);
    r.y = fmaxf(fmaf(dv, acc.y, bb.y), 0.0f);
    if (obf) {
        ((unsigned*)out)[vb] = bfr(r.x) | (bfr(r.y) << 16);
    } else {
        ((float2*)out)[vb] = r;
    }
}

// ---------------- launch ----------------

extern "C" void kernel_launch(void* const* d_in, const int* in_sizes, int n_in,
                              void* d_out, int out_size, void* d_ws, size_t ws_size,
                              hipStream_t stream) {
    const float* x  = (const float*)d_in[0];
    const int*   ei = (const int*)d_in[1];   // [2, E] int32
    const float* W1 = (const float*)d_in[2];
    const float* b1 = (const float*)d_in[3];
    const float* W2 = (const float*)d_in[4];
    const float* b2 = (const float*)d_in[5];

    int N = in_sizes[0] / FD;
    int E = in_sizes[1] / 2;
    const int* src = ei;
    const int* dst = ei + E;
    int K = (N + (1 << BSH) - 1) >> BSH;     // buckets (<= 512 assumed)
    int PB = (E + CH - 1) / CH;              // partition blocks

    char* base = (char*)d_ws;
    size_t off = 0;
    auto align256 = [](size_t v) { return (v + 255) & ~(size_t)255; };
    int*            rp    = (int*)(base + off);            off += align256((size_t)(N + 1) * 4);
    float*          dis   = (float*)(base + off);          off += align256((size_t)N * 4);
    int*            total = (int*)(base + off);            off += align256(512 * 4);
    int*            bbase = (int*)(base + off);            off += align256(513 * 4);
    unsigned short* w1t   = (unsigned short*)(base + off); off += align256((size_t)FD * FD * 2);
    unsigned short* w2t   = (unsigned short*)(base + off); off += align256((size_t)FD * FD * 2);
    int*            col   = (int*)(base + off);            off += align256((size_t)E * 4);
    unsigned short* hbuf  = (unsigned short*)(base + off); off += align256((size_t)N * FD * 2);
    unsigned short* z1    = (unsigned short*)(base + off); off += align256((size_t)N * FD * 2);
    int*            pairs = (int*)(base + off);            off += align256((size_t)E * 4);
    int*            lstartG = (int*)hbuf;   // overlay: dead until gemm1 writes hbuf
    int*            lstartT = (int*)z1;     // overlay: dead until agg1 writes z1
    (void)ws_size; (void)n_in; (void)out_size;

    (void)hipMemsetAsync(total, 0, 512 * 4, stream);
    partition_kernel<<<PB, 256, 0, stream>>>(src, dst, lstartG, total, pairs, E, K);
    totscan_kernel  <<<1, 512, 0, stream>>>(total, bbase, rp, K, E, N);
    dim3 trb(32, 8);
    dim3 trg((K + 1 + 31) / 32, (PB + 31) / 32);
    tr_kernel       <<<trg, trb, 0, stream>>>(lstartG, lstartT, PB, K + 1);
    build_kernel    <<<K, 256, 0, stream>>>(pairs, lstartT, bbase, rp, dis, col, N, PB, K);

    wt_kernel<<<2 * FD, FD, 0, stream>>>(W1, w1t, W2, w2t);

    dim3 aggBlk(64, 4);
    int aggGrid = (N + 3) / 4;
    int gemmGrid = (N + 127) / 128;

    gemm_mfma_f32 <<<gemmGrid, 256, 0, stream>>>(x, w1t, dis, hbuf, N);
    agg_kernel<<<aggGrid, aggBlk, 0, stream>>>((const unsigned*)hbuf, dis, rp, col,
                                               (const float2*)b1, z1, N, 1);
    gemm_mfma_bf16<<<gemmGrid, 256, 0, stream>>>(z1, w2t, dis, hbuf, N);
    agg_kernel<<<aggGrid, aggBlk, 0, stream>>>((const unsigned*)hbuf, dis, rp, col,
                                               (const float2*)b2, d_out, N, 0);
}